// Round 1
// baseline (750.247 us; speedup 1.0000x reference)
//
#include <hip/hip_runtime.h>
#include <hip/hip_bf16.h>
#include <stdint.h>

// ---------------- problem constants ----------------
#define N_TOK 8192
#define DIM   1024
#define FF    4096
#define NEXP  8

// ---------------- workspace layout (bytes) ----------------
#define OFF_COUNTS   0ull            // 8 * 4
#define OFF_NTILES   64ull           // 4
#define OFF_PNT      128ull          // 8 * 4 (per-expert tile counts)
#define OFF_TABLE    4096ull         // 256 * 16 combined tile table
#define OFF_PTABLE   8192ull         // 8 * 64 * 16 per-expert tables
#define OFF_IDX      16384ull        // 8*8192*4 token index lists
#define OFF_GATE     278528ull       // 8*8192*4 gate lists
#define OFF_XB       1048576ull      // x bf16: 8192*1024*2 = 16,777,216
#define OFF_H        17825792ull     // h bf16
// mode0: h = 8192*4096*2  = 67,108,864  -> need  84,934,656
// mode1: h = 17408*4096*2 = 142,606,336 -> need 160,432,128
#define OFF_W1B      160432128ull    // 8*4096*1024*2 = 67,108,864
#define OFF_W2B      227540992ull
#define NEED0        84934656ull
#define NEED1        160432128ull
#define NEED2        294649856ull

typedef __attribute__((ext_vector_type(8))) short s16x8;   // 8 bf16 (4 VGPR) MFMA frag
typedef __attribute__((ext_vector_type(4))) float f32x4;   // MFMA accum

__device__ __forceinline__ unsigned short f2bf(float f) {
  union { float f; unsigned int u; } v; v.f = f;
  unsigned int u = v.u;
  unsigned int r = (u + 0x7FFFu + ((u >> 16) & 1u)) >> 16;  // RNE
  return (unsigned short)r;
}

// exact-ish gelu: 0.5*x*(1+erf(x/sqrt2)), erf via A&S 7.1.26 (|err|<1.5e-7)
__device__ __forceinline__ float gelu_f(float x) {
  float s = x * 0.70710678118654752f;
  float a = fabsf(s);
  float t = 1.0f / fmaf(0.3275911f, a, 1.0f);
  float p = t * fmaf(t, fmaf(t, fmaf(t, fmaf(t, 1.061405429f, -1.453152027f),
                                     1.421413741f), -0.284496736f), 0.254829592f);
  float e = __expf(-a * a);
  float erf_a = 1.0f - p * e;
  float erf_s = (s >= 0.0f) ? erf_a : -erf_a;
  return 0.5f * x * (1.0f + erf_s);
}

// async global -> LDS, 16B per lane (dest must be wave-uniform-base + lane*16)
__device__ __forceinline__ void load_lds16(const void* g, void* l) {
  __builtin_amdgcn_global_load_lds(
      (const __attribute__((address_space(1))) unsigned int*)g,
      (__attribute__((address_space(3))) unsigned int*)l, 16, 0, 0);
}

// ---------------- f32 -> bf16 bulk convert ----------------
__global__ __launch_bounds__(256) void cvt_f32_bf16(const float4* __restrict__ in,
                                                    ushort4* __restrict__ out, int n4) {
  int i = blockIdx.x * 256 + threadIdx.x;
  int stride = gridDim.x * 256;
  for (; i < n4; i += stride) {
    float4 f = in[i];
    ushort4 u;
    u.x = f2bf(f.x); u.y = f2bf(f.y); u.z = f2bf(f.z); u.w = f2bf(f.w);
    out[i] = u;
  }
}

// ---------------- router: 1 wave per token ----------------
__global__ __launch_bounds__(256) void router_kernel(
    const float* __restrict__ x, const float* __restrict__ rw,
    int* __restrict__ counts, int* __restrict__ idx_list, float* __restrict__ gate_list) {
  int wid = threadIdx.x >> 6;
  int lane = threadIdx.x & 63;
  int token = blockIdx.x * 4 + wid;

  const float4* xr = (const float4*)(x + (size_t)token * DIM);
  float p[NEXP];
#pragma unroll
  for (int e = 0; e < NEXP; ++e) p[e] = 0.f;
#pragma unroll
  for (int c = 0; c < 4; ++c) {
    float4 xv = xr[c * 64 + lane];
#pragma unroll
    for (int e = 0; e < NEXP; ++e) {
      float4 wv = ((const float4*)(rw + (size_t)e * DIM))[c * 64 + lane];
      p[e] += xv.x * wv.x + xv.y * wv.y + xv.z * wv.z + xv.w * wv.w;
    }
  }
#pragma unroll
  for (int e = 0; e < NEXP; ++e) {
    float v = p[e];
#pragma unroll
    for (int off = 32; off > 0; off >>= 1) v += __shfl_xor(v, off, 64);
    p[e] = v;
  }
  if (lane == 0) {
    int e0 = 0; float v0 = p[0];
#pragma unroll
    for (int e = 1; e < NEXP; ++e) if (p[e] > v0) { v0 = p[e]; e0 = e; }
    int e1 = (e0 == 0) ? 1 : 0; float v1 = -3.4e38f;
#pragma unroll
    for (int e = 0; e < NEXP; ++e) if (e != e0 && p[e] > v1) { v1 = p[e]; e1 = e; }
    float ex = __expf(v1 - v0);
    float g0 = 1.0f / (1.0f + ex);
    float g1 = ex / (1.0f + ex);
    int p0 = atomicAdd(&counts[e0], 1);
    idx_list[e0 * N_TOK + p0] = token;
    gate_list[e0 * N_TOK + p0] = g0;
    int p1 = atomicAdd(&counts[e1], 1);
    idx_list[e1 * N_TOK + p1] = token;
    gate_list[e1 * N_TOK + p1] = g1;
  }
}

// ---------------- schedule: counts -> tile tables ----------------
__global__ void schedule_kernel(const int* __restrict__ counts, int4* __restrict__ table,
                                int* __restrict__ ntiles, int4* __restrict__ ptable,
                                int* __restrict__ pntiles) {
  if (threadIdx.x == 0 && blockIdx.x == 0) {
    int tt = 0, gb = 0;
    for (int e = 0; e < NEXP; ++e) {
      int c = counts[e];
      int t = (c + 127) >> 7;
      for (int i = 0; i < t; ++i) { table[tt] = make_int4(e, i << 7, gb + (i << 7), 0); tt++; }
      gb += t << 7;
      pntiles[e] = t;
      for (int i = 0; i < t; ++i) ptable[e * 64 + i] = make_int4(e, i << 7, i << 7, 0);
    }
    *ntiles = tt;
  }
}

// ---------------- grouped GEMM, 128x128 tile, BK=64, 4 waves ----------------
// EPI==1: C = gelu(A_gathered @ W^T) -> Hout (bf16).  A rows gathered via idx_list.
// EPI==2: atomicAdd(Out[token], gate * (A @ W^T)).    A rows = h at gbase+local.
template <int KDIM, bool BF32, int EPI>
__global__ __launch_bounds__(256, 2) void moe_gemm(
    const unsigned short* __restrict__ Abase, const unsigned short* __restrict__ Bb,
    const float* __restrict__ Bf, unsigned short* __restrict__ Hout,
    float* __restrict__ Out, const int* __restrict__ idx_list,
    const float* __restrict__ gate_list, const int* __restrict__ counts,
    const int4* __restrict__ table, const int* __restrict__ n_tiles) {
  if ((int)blockIdx.y >= *n_tiles) return;
  int4 te = table[blockIdx.y];
  const int e = te.x;
  const int row_start = te.y;
  const int gbase = te.z;
  const int ce = counts[e];

  const int tid = threadIdx.x;
  const int wid = tid >> 6;
  const int lane = tid & 63;
  const int colT = blockIdx.x * 128;

  __shared__ unsigned short Al[128][64];
  __shared__ unsigned short Bl[128][64];

  const int sr = tid >> 3;        // staging row 0..31 (x4 issues)
  const int sc = (tid & 7) * 8;   // staging col (elems)

  const char* Abytes = (const char*)Abase;
  size_t aoff[4];
#pragma unroll
  for (int i = 0; i < 4; ++i) {
    if constexpr (EPI == 1) {
      int r = row_start + i * 32 + sr;
      int rc = (r < ce) ? r : (ce - 1);             // clamp padded rows
      int tok = idx_list[e * N_TOK + rc];
      aoff[i] = ((size_t)tok * KDIM + sc) * 2;
    } else {
      aoff[i] = ((size_t)(gbase + i * 32 + sr) * KDIM + sc) * 2;
    }
  }
  const char* Bbytes = BF32 ? (const char*)Bf : (const char*)Bb;
  size_t boff[4];
#pragma unroll
  for (int i = 0; i < 4; ++i) {
    size_t br = (size_t)(colT + i * 32 + sr);
    boff[i] = ((size_t)e * FF * DIM + br * KDIM + sc) * (BF32 ? 4 : 2);
  }

  f32x4 acc[4][4] = {};

  const int wr = (wid >> 1) * 64;
  const int wc = (wid & 1) * 64;
  const int r16 = lane & 15;
  const int kg = lane >> 4;

  for (int kk = 0; kk < KDIM; kk += 64) {
#pragma unroll
    for (int i = 0; i < 4; ++i)
      load_lds16(Abytes + aoff[i] + (size_t)kk * 2, &Al[i * 32 + sr][sc]);
    if constexpr (!BF32) {
#pragma unroll
      for (int i = 0; i < 4; ++i)
        load_lds16(Bbytes + boff[i] + (size_t)kk * 2, &Bl[i * 32 + sr][sc]);
    } else {
#pragma unroll
      for (int i = 0; i < 4; ++i) {
        const float* bp = (const float*)(Bbytes + boff[i] + (size_t)kk * 4);
        float4 f0 = *(const float4*)bp;
        float4 f1 = *(const float4*)(bp + 4);
        ushort4 u0, u1;
        u0.x = f2bf(f0.x); u0.y = f2bf(f0.y); u0.z = f2bf(f0.z); u0.w = f2bf(f0.w);
        u1.x = f2bf(f1.x); u1.y = f2bf(f1.y); u1.z = f2bf(f1.z); u1.w = f2bf(f1.w);
        *(ushort4*)&Bl[i * 32 + sr][sc] = u0;
        *(ushort4*)&Bl[i * 32 + sr][sc + 4] = u1;
      }
    }
    __syncthreads();
#pragma unroll
    for (int kf = 0; kf < 2; ++kf) {
      const int k0 = kf * 32 + kg * 8;
      s16x8 a[4], b[4];
#pragma unroll
      for (int m = 0; m < 4; ++m) a[m] = *(const s16x8*)&Al[wr + m * 16 + r16][k0];
#pragma unroll
      for (int n = 0; n < 4; ++n) b[n] = *(const s16x8*)&Bl[wc + n * 16 + r16][k0];
#pragma unroll
      for (int m = 0; m < 4; ++m)
#pragma unroll
        for (int n = 0; n < 4; ++n)
          acc[m][n] = __builtin_amdgcn_mfma_f32_16x16x32_bf16(a[m], b[n], acc[m][n], 0, 0, 0);
    }
    __syncthreads();
  }

  if constexpr (EPI == 1) {
#pragma unroll
    for (int m = 0; m < 4; ++m) {
      const int row0 = wr + m * 16 + kg * 4;
#pragma unroll
      for (int j = 0; j < 4; ++j) {
        size_t hrow = (size_t)(gbase + row0 + j) * FF;
#pragma unroll
        for (int n = 0; n < 4; ++n) {
          int col = colT + wc + n * 16 + r16;
          Hout[hrow + col] = f2bf(gelu_f(acc[m][n][j]));
        }
      }
    }
  } else {
#pragma unroll
    for (int m = 0; m < 4; ++m) {
      const int row0 = wr + m * 16 + kg * 4;
#pragma unroll
      for (int j = 0; j < 4; ++j) {
        int r = row_start + row0 + j;
        if (r < ce) {
          int tok = idx_list[e * N_TOK + r];
          float gate = gate_list[e * N_TOK + r];
          float* orow = Out + (size_t)tok * DIM;
#pragma unroll
          for (int n = 0; n < 4; ++n) {
            int col = colT + wc + n * 16 + r16;
            atomicAdd(&orow[col], acc[m][n][j] * gate);
          }
        }
      }
    }
  }
}

// ---------------- launch ----------------
extern "C" void kernel_launch(void* const* d_in, const int* in_sizes, int n_in,
                              void* d_out, int out_size, void* d_ws, size_t ws_size,
                              hipStream_t stream) {
  const float* x  = (const float*)d_in[0];
  const float* rw = (const float*)d_in[1];
  const float* w1 = (const float*)d_in[2];
  const float* w2 = (const float*)d_in[3];
  float* out = (float*)d_out;
  char* ws = (char*)d_ws;

  if (ws_size < NEED0) return;  // cannot run correctly; fail loudly via absmax

  int*   counts    = (int*)(ws + OFF_COUNTS);
  int*   ntiles    = (int*)(ws + OFF_NTILES);
  int*   pntiles   = (int*)(ws + OFF_PNT);
  int4*  table     = (int4*)(ws + OFF_TABLE);
  int4*  ptable    = (int4*)(ws + OFF_PTABLE);
  int*   idx_list  = (int*)(ws + OFF_IDX);
  float* gate_list = (float*)(ws + OFF_GATE);
  unsigned short* xb  = (unsigned short*)(ws + OFF_XB);
  unsigned short* h   = (unsigned short*)(ws + OFF_H);
  unsigned short* w1b = (unsigned short*)(ws + OFF_W1B);
  unsigned short* w2b = (unsigned short*)(ws + OFF_W2B);

  const int mode = (ws_size >= NEED2) ? 2 : (ws_size >= NEED1 ? 1 : 0);

  hipMemsetAsync(d_out, 0, (size_t)N_TOK * DIM * sizeof(float), stream);
  hipMemsetAsync(ws, 0, 256, stream);  // counts + ntiles

  cvt_f32_bf16<<<1024, 256, 0, stream>>>((const float4*)x, (ushort4*)xb, N_TOK * DIM / 4);
  if (mode == 2) {
    cvt_f32_bf16<<<2048, 256, 0, stream>>>((const float4*)w1, (ushort4*)w1b, NEXP * FF * DIM / 4);
    cvt_f32_bf16<<<2048, 256, 0, stream>>>((const float4*)w2, (ushort4*)w2b, NEXP * FF * DIM / 4);
  }
  router_kernel<<<N_TOK / 4, 256, 0, stream>>>(x, rw, counts, idx_list, gate_list);
  schedule_kernel<<<1, 64, 0, stream>>>(counts, table, ntiles, ptable, pntiles);

  if (mode == 2) {
    moe_gemm<DIM, false, 1><<<dim3(FF / 128, 136), 256, 0, stream>>>(
        xb, w1b, nullptr, h, nullptr, idx_list, gate_list, counts, table, ntiles);
    moe_gemm<FF, false, 2><<<dim3(DIM / 128, 136), 256, 0, stream>>>(
        h, w2b, nullptr, nullptr, out, idx_list, gate_list, counts, table, ntiles);
  } else if (mode == 1) {
    moe_gemm<DIM, true, 1><<<dim3(FF / 128, 136), 256, 0, stream>>>(
        xb, nullptr, w1, h, nullptr, idx_list, gate_list, counts, table, ntiles);
    moe_gemm<FF, true, 2><<<dim3(DIM / 128, 136), 256, 0, stream>>>(
        h, nullptr, w2, nullptr, out, idx_list, gate_list, counts, table, ntiles);
  } else {
    for (int e = 0; e < NEXP; ++e) {
      moe_gemm<DIM, true, 1><<<dim3(FF / 128, 64), 256, 0, stream>>>(
          xb, nullptr, w1, h, nullptr, idx_list, gate_list, counts, ptable + e * 64, pntiles + e);
      moe_gemm<FF, true, 2><<<dim3(DIM / 128, 64), 256, 0, stream>>>(
          h, nullptr, w2, nullptr, out, idx_list, gate_list, counts, ptable + e * 64, pntiles + e);
    }
  }
}